// Round 5
// baseline (387.829 us; speedup 1.0000x reference)
//
#include <hip/hip_runtime.h>

typedef unsigned short u16;
typedef unsigned int u32;
typedef short s8v __attribute__((ext_vector_type(8)));    // 8 x bf16 bits (4 VGPRs)
typedef float f16v __attribute__((ext_vector_type(16)));  // 32x32 MFMA accumulator
typedef u32 u32x4 __attribute__((ext_vector_type(4)));

// ---------- helpers ----------
__device__ __forceinline__ u16 f2bf(float f) {
    u32 u = __float_as_uint(f);
    u += 0x7FFFu + ((u >> 16) & 1u);   // round-to-nearest-even
    return (u16)(u >> 16);
}

__device__ __forceinline__ void async_load16(const u16* g, u16* l) {
    // global -> LDS DMA, 16B per lane; LDS dest = wave-uniform base + lane*16
    __builtin_amdgcn_global_load_lds(
        (const __attribute__((address_space(1))) u32*)g,
        (__attribute__((address_space(3))) u32*)l,
        16, 0, 0);
}

// ---------- kernel 0: style (once per b, coalesced mod_w via LDS) ----------
__global__ void style_kernel(const float* __restrict__ norm_feat,  // [8][64]
                             const float* __restrict__ mod_w,      // [256][64]
                             const float* __restrict__ mod_b,      // [256]
                             float* __restrict__ style) {          // [8][256]
    __shared__ float nf[64];
    __shared__ float mw[256][65];
    const int b = blockIdx.x;
    const int tid = threadIdx.x;

    if (tid < 64) nf[tid] = norm_feat[b * 64 + tid];
    #pragma unroll
    for (int i = 0; i < 64; ++i) {
        int idx = i * 256 + tid;
        mw[idx >> 6][idx & 63] = mod_w[idx];
    }
    __syncthreads();

    float s = mod_b[tid];
    #pragma unroll 8
    for (int d = 0; d < 64; ++d) s += nf[d] * mw[tid][d];
    style[b * 256 + tid] = s;
}

// ---------- kernel 1: demod + modulated bf16 weights ----------
// grid (256 co, 8 b), 256 threads (thread = ci)
// Wmod layout for 32x32x16 fragments:
//   [b][t][cob=co>>5 (8)][cib=ci>>4 (16)][lane=(co&31)+32*((ci>>3)&1)][elem=ci&7]
__global__ void modulate_kernel(const float* __restrict__ style,   // [8][256]
                                const float* __restrict__ weight,  // [256][256][9]
                                u16* __restrict__ Wmod) {
    const int co = blockIdx.x;
    const int b  = blockIdx.y;
    const int ci = threadIdx.x;

    __shared__ float red[256];

    const float s = style[b * 256 + ci];

    float w9[9];
    const float* wp = weight + ((size_t)co * 256 + ci) * 9;
    float sq = 0.f;
    #pragma unroll
    for (int t = 0; t < 9; ++t) { w9[t] = wp[t]; sq += w9[t] * w9[t]; }

    red[ci] = sq * s * s;
    __syncthreads();
    for (int off = 128; off > 0; off >>= 1) {
        if (ci < off) red[ci] += red[ci + off];
        __syncthreads();
    }
    const float scale = 1.0f / 48.0f;              // 1/sqrt(256*9)
    const float demod = rsqrtf(scale * scale * red[0] + 1e-8f);
    const float coef  = scale * s * demod;

    // t=0 base; per-t stride = 8*16*64*8 = 65536 u16
    const size_t tile = (((size_t)b * 9 * 8 + (co >> 5)) * 16 + (ci >> 4)) * 512
                      + (size_t)((co & 31) + 32 * ((ci >> 3) & 1)) * 8 + (ci & 7);
    #pragma unroll
    for (int t = 0; t < 9; ++t) {
        Wmod[tile + (size_t)t * 65536] = f2bf(w9[t] * coef);
    }
}

// ---------- kernel 2: NCHW fp32 -> blocked-NHWC bf16 ----------
// feaT layout: [b][y][ch(16)][cg(2)][x(128)][cil(8)] bf16   (c = ch*16 + cg*8 + cil)
__global__ __launch_bounds__(256) void transpose_kernel(const float* __restrict__ fea,
                                                        u16* __restrict__ feaT) {
    __shared__ float lds_t[64][132];   // row = 528B -> float4-aligned, 2-way banks
    const int y = blockIdx.x;
    const int b = blockIdx.y;
    const int tid = threadIdx.x;

    for (int c0 = 0; c0 < 256; c0 += 64) {
        #pragma unroll
        for (int r = 0; r < 8; ++r) {
            int i  = r * 256 + tid;       // 0..2047
            int c  = i >> 5;              // 0..63
            int x4 = i & 31;              // float4 index
            float4 v = *(const float4*)&fea[(((size_t)(b * 256 + c0 + c)) * 128 + y) * 128 + x4 * 4];
            *(float4*)&lds_t[c][x4 * 4] = v;
        }
        __syncthreads();
        #pragma unroll
        for (int jj = 0; jj < 4; ++jj) {
            int p   = jj * 256 + tid;     // 0..1023
            int x   = p & 127;
            int g   = p >> 7;             // 0..7 (granule of 8 c)
            int cb8 = g * 8;
            u32x4 wv;
            #pragma unroll
            for (int k = 0; k < 4; ++k) {
                float f0 = lds_t[cb8 + 2 * k][x];
                float f1 = lds_t[cb8 + 2 * k + 1][x];
                wv[k] = (u32)f2bf(f0) | ((u32)f2bf(f1) << 16);
            }
            int c  = c0 + cb8;
            int ch = c >> 4;
            int cg = (c >> 3) & 1;
            size_t off = (((((size_t)b * 128 + y) * 16 + ch) * 2 + cg) * 128 + x) * 8;
            *(u32x4*)&feaT[off] = wv;
        }
        __syncthreads();
    }
}

// ---------- kernel 3: MFMA conv (shift-GEMM), 32x32x16, 4x2 wave tile ----------
// grid (64 y-pairs, 8 b), 512 threads = 8 waves (mw2 x nw2 x yw2)
// wave tile: 128 co x 64 px x 1 row -> 4 A-frags x 2 B-frags = 8 MFMA/tap (4:1 vs ds_read)
__global__ __launch_bounds__(512, 2) void conv_mfma(
        const u16* __restrict__ Wmod,   // fragment-ordered, see modulate_kernel
        const u16* __restrict__ feaT,   // [8][128][16][2][128][8] bf16
        float* __restrict__ out) {      // [8][256][128][128]
    // per-parity: 8192 u16 fea data ([row4][cg2][x128][8ci]) + 24 u16 zero pad
    __shared__ u16 lds[2][8216];        // 32,864 B total

    // XCD swizzle: 512 wgs = 8 XCDs x 64; each XCD owns one batch b
    const int lin = blockIdx.x + 64 * blockIdx.y;
    const int yp  = lin >> 3;           // y-pair: rows 2*yp, 2*yp+1
    const int b   = lin & 7;            // = XCD id for round-robin dispatch

    const int tid  = threadIdx.x;
    const int lane = tid & 63;
    const int wave = tid >> 6;          // 0..7
    const int mw  = wave & 1;           // co half (128 of 256)
    const int nw  = (wave >> 1) & 1;    // pixel half (64)
    const int yw  = wave >> 2;          // output row within pair
    const int l31 = lane & 31;
    const int l5  = lane >> 5;          // k-group (8 ci)

    // zero both parity pads (24 u16 each)
    if (tid < 24) { lds[0][8192 + tid] = 0; lds[1][8192 + tid] = 0; }

    const int y_out = 2 * yp + yw;

    // ---- precompute all B-side LDS offsets (u16 units, rel. to parity base) ----
    // tap (kh,kw), j: addr = base[kh][j] + kw*8   (kw folded into ds_read imm)
    // boundary combos (kw=0,j=0) and (kw=2,j=1) pre-resolved per lane; y-edge
    // validity folded in (whole row -> zero pad at 8192).
    const int xb0 = nw * 64 + l31 - 1;
    int ofj0[3], ofj1[3], bq0[3], bq2[3];
    #pragma unroll
    for (int kh = 0; kh < 3; ++kh) {
        const int rr = kh + yw;
        const int rowb = ((rr * 2 + l5) * 128) * 8;
        const bool rok = (kh == 0) ? (y_out > 0) : (kh == 2 ? (y_out < 127) : true);
        const int o0 = rowb + xb0 * 8;      // j=0 base at kw=0
        const int o1 = o0 + 256;            // j=1 base at kw=0
        ofj0[kh] = rok ? o0 : 8192;
        ofj1[kh] = rok ? o1 : 8192;
        bq0[kh]  = (rok && xb0 >= 0)       ? o0        : 8192;   // (kw=0,j=0)
        bq2[kh]  = (rok && xb0 + 34 < 128) ? (o1 + 16) : 8192;   // (kw=2,j=1), +16 = kw*8
    }

    // A-side: cob = mw*4 + i (i=0..3); strides (u16): t=65536, cob=8192, cib=512
    const u16* Abase = Wmod + (size_t)b * 9 * 65536
                            + (size_t)(mw * 4) * 8192 + (size_t)lane * 8;

    auto loadA = [&](int t, int i, int ch) -> s8v {
        return *(const s8v*)(Abase + (size_t)t * 65536 + (size_t)i * 8192 + (size_t)ch * 512);
    };

    // stage one 16-ci chunk: 16 contiguous 1024B DMA units = r(4) x cg(2) x xq(2)
    auto stage = [&](int buf, int ch) {
        u16* ldsb = &lds[buf][0];
        #pragma unroll
        for (int i = 0; i < 2; ++i) {
            int u  = wave + 8 * i;       // 0..15, wave-uniform
            int r  = u >> 2;             // 0..3
            int cg = (u >> 1) & 1;
            int xq = u & 1;
            int gy = 2 * yp - 1 + r;
            if ((unsigned)gy < 128u) {
                const u16* g = feaT +
                    (((((size_t)b * 128 + gy) * 16 + ch) * 2 + cg) * 128 + xq * 64) * 8
                    + (size_t)lane * 8;
                async_load16(g, ldsb + ((r * 2 + cg) * 128 + xq * 64) * 8);
            }
        }
    };

    f16v acc[4][2];
    #pragma unroll
    for (int i = 0; i < 4; ++i)
        #pragma unroll
        for (int j = 0; j < 2; ++j) acc[i][j] = (f16v)0.0f;

    // A-fragment ring: distance-3 prefetch, 9 taps % 3 == 0 -> static ring index
    s8v fr[3][4];

    // prologue: stage chunk 0, preload taps 0..2 of chunk 0 (full drain once, OK)
    stage(0, 0);
    #pragma unroll
    for (int g = 0; g < 3; ++g)
        #pragma unroll
        for (int i = 0; i < 4; ++i) fr[g][i] = loadA(g, i, 0);
    __syncthreads();

    #pragma unroll 1
    for (int ch = 0; ch < 16; ++ch) {
        const u16* basep = &lds[ch & 1][0];
        #pragma unroll
        for (int t = 0; t < 9; ++t) {
            const int kh = t / 3, kw = t % 3;

            s8v bfr[2];
            {
                const u16* a0 = (kw == 0) ? (basep + bq0[kh]) : (basep + ofj0[kh] + kw * 8);
                const u16* a1 = (kw == 2) ? (basep + bq2[kh]) : (basep + ofj1[kh] + kw * 8);
                bfr[0] = *(const s8v*)a0;
                bfr[1] = *(const s8v*)a1;
            }

            __builtin_amdgcn_s_setprio(1);
            #pragma unroll
            for (int i = 0; i < 4; ++i)
                #pragma unroll
                for (int j = 0; j < 2; ++j)
                    acc[i][j] = __builtin_amdgcn_mfma_f32_32x32x16_bf16(
                        fr[t % 3][i], bfr[j], acc[i][j], 0, 0, 0);
            __builtin_amdgcn_s_setprio(0);

            // refill ring slot (t%3) with the fragments needed 3 taps ahead.
            // FIFO: t4/t5 refills are consumed at t7/t8 -> their waits drain the
            // t3 stage DMAs; only taps 6-8 refills (12 entries) live at chunk end.
            if (t < 6) {
                #pragma unroll
                for (int i = 0; i < 4; ++i) fr[t % 3][i] = loadA(t + 3, i, ch);
            } else if (ch < 15) {
                #pragma unroll
                for (int i = 0; i < 4; ++i) fr[t % 3][i] = loadA(t - 6, i, ch + 1);
            }

            if (t == 3 && ch < 15) {
                // pin the DMA's position in the vmem FIFO (vmcnt(12) proof relies on it)
                __builtin_amdgcn_sched_barrier(0);
                stage((ch + 1) & 1, ch + 1);
                __builtin_amdgcn_sched_barrier(0);
            }
        }

        if (ch < 15) {
            // counted-vmcnt barrier (T4): keep the 12 next-chunk A-refills in
            // flight across the barrier; everything older (incl. the stage
            // DMAs) is forced complete. No full drain in the main loop.
            asm volatile("s_waitcnt vmcnt(12)" ::: "memory");
            __builtin_amdgcn_sched_barrier(0);
            __builtin_amdgcn_s_barrier();
            __builtin_amdgcn_sched_barrier(0);
        }
    }

    // epilogue: C/D layout col(n=pixel)=lane&31, row(m=co)=(reg&3)+8*(reg>>2)+4*(lane>>5)
    const int x_base = nw * 64 + l31;
    #pragma unroll
    for (int i = 0; i < 4; ++i) {
        #pragma unroll
        for (int j = 0; j < 2; ++j) {
            #pragma unroll
            for (int reg = 0; reg < 16; ++reg) {
                int co = mw * 128 + i * 32 + (reg & 3) + 8 * (reg >> 2) + 4 * l5;
                out[(((size_t)(b * 256 + co) * 128 + y_out) * 128) + x_base + j * 32] = acc[i][j][reg];
            }
        }
    }
}

// ---------- launch ----------
extern "C" void kernel_launch(void* const* d_in, const int* in_sizes, int n_in,
                              void* d_out, int out_size, void* d_ws, size_t ws_size,
                              hipStream_t stream) {
    const float* fea       = (const float*)d_in[0];
    const float* norm_feat = (const float*)d_in[1];
    const float* mod_w     = (const float*)d_in[2];
    const float* mod_b     = (const float*)d_in[3];
    const float* weight    = (const float*)d_in[4];
    float* out = (float*)d_out;

    // workspace: Wmod bf16 = 9 MiB, then feaT bf16 = 64 MiB.
    // style (8 KiB fp32) lives at the head of the feaT region (serialized reuse).
    u16* Wmod = (u16*)d_ws;
    u16* feaT = (u16*)((char*)d_ws + 9u * 1024u * 1024u);
    float* style = (float*)feaT;

    style_kernel<<<dim3(8), 256, 0, stream>>>(norm_feat, mod_w, mod_b, style);
    modulate_kernel<<<dim3(256, 8), 256, 0, stream>>>(style, weight, Wmod);
    transpose_kernel<<<dim3(128, 8), 256, 0, stream>>>(fea, feaT);
    conv_mfma<<<dim3(64, 8), 512, 0, stream>>>(Wmod, feaT, out);
}

// Round 6
// 381.747 us; speedup vs baseline: 1.0159x; 1.0159x over previous
//
#include <hip/hip_runtime.h>

typedef unsigned short u16;
typedef unsigned int u32;
typedef short s8v __attribute__((ext_vector_type(8)));    // 8 x bf16 bits (4 VGPRs)
typedef float f16v __attribute__((ext_vector_type(16)));  // 32x32 MFMA accumulator
typedef u32 u32x4 __attribute__((ext_vector_type(4)));

// ---------- helpers ----------
__device__ __forceinline__ u16 f2bf(float f) {
    u32 u = __float_as_uint(f);
    u += 0x7FFFu + ((u >> 16) & 1u);   // round-to-nearest-even
    return (u16)(u >> 16);
}

__device__ __forceinline__ void async_load16(const u16* g, u16* l) {
    // global -> LDS DMA, 16B per lane; LDS dest = wave-uniform base + lane*16
    __builtin_amdgcn_global_load_lds(
        (const __attribute__((address_space(1))) u32*)g,
        (__attribute__((address_space(3))) u32*)l,
        16, 0, 0);
}

// ---------- kernel 0: style (once per b, coalesced mod_w via LDS) ----------
__global__ void style_kernel(const float* __restrict__ norm_feat,  // [8][64]
                             const float* __restrict__ mod_w,      // [256][64]
                             const float* __restrict__ mod_b,      // [256]
                             float* __restrict__ style) {          // [8][256]
    __shared__ float nf[64];
    __shared__ float mw[256][65];
    const int b = blockIdx.x;
    const int tid = threadIdx.x;

    if (tid < 64) nf[tid] = norm_feat[b * 64 + tid];
    #pragma unroll
    for (int i = 0; i < 64; ++i) {
        int idx = i * 256 + tid;
        mw[idx >> 6][idx & 63] = mod_w[idx];
    }
    __syncthreads();

    float s = mod_b[tid];
    #pragma unroll 8
    for (int d = 0; d < 64; ++d) s += nf[d] * mw[tid][d];
    style[b * 256 + tid] = s;
}

// ---------- kernel 1: demod + modulated bf16 weights ----------
// grid (256 co, 8 b), 256 threads (thread = ci)
// Wmod layout for 32x32x16 fragments:
//   [b][t][cob=co>>5 (8)][cib=ci>>4 (16)][lane=(co&31)+32*((ci>>3)&1)][elem=ci&7]
__global__ void modulate_kernel(const float* __restrict__ style,   // [8][256]
                                const float* __restrict__ weight,  // [256][256][9]
                                u16* __restrict__ Wmod) {
    const int co = blockIdx.x;
    const int b  = blockIdx.y;
    const int ci = threadIdx.x;

    __shared__ float red[256];

    const float s = style[b * 256 + ci];

    float w9[9];
    const float* wp = weight + ((size_t)co * 256 + ci) * 9;
    float sq = 0.f;
    #pragma unroll
    for (int t = 0; t < 9; ++t) { w9[t] = wp[t]; sq += w9[t] * w9[t]; }

    red[ci] = sq * s * s;
    __syncthreads();
    for (int off = 128; off > 0; off >>= 1) {
        if (ci < off) red[ci] += red[ci + off];
        __syncthreads();
    }
    const float scale = 1.0f / 48.0f;              // 1/sqrt(256*9)
    const float demod = rsqrtf(scale * scale * red[0] + 1e-8f);
    const float coef  = scale * s * demod;

    // t=0 base; per-t stride = 8*16*64*8 = 65536 u16
    const size_t tile = (((size_t)b * 9 * 8 + (co >> 5)) * 16 + (ci >> 4)) * 512
                      + (size_t)((co & 31) + 32 * ((ci >> 3) & 1)) * 8 + (ci & 7);
    #pragma unroll
    for (int t = 0; t < 9; ++t) {
        Wmod[tile + (size_t)t * 65536] = f2bf(w9[t] * coef);
    }
}

// ---------- kernel 2: NCHW fp32 -> blocked-NHWC bf16 ----------
// feaT layout: [b][y][ch(16)][cg(2)][x(128)][cil(8)] bf16   (c = ch*16 + cg*8 + cil)
__global__ __launch_bounds__(256) void transpose_kernel(const float* __restrict__ fea,
                                                        u16* __restrict__ feaT) {
    __shared__ float lds_t[64][132];   // row = 528B -> float4-aligned, 2-way banks
    const int y = blockIdx.x;
    const int b = blockIdx.y;
    const int tid = threadIdx.x;

    for (int c0 = 0; c0 < 256; c0 += 64) {
        #pragma unroll
        for (int r = 0; r < 8; ++r) {
            int i  = r * 256 + tid;       // 0..2047
            int c  = i >> 5;              // 0..63
            int x4 = i & 31;              // float4 index
            float4 v = *(const float4*)&fea[(((size_t)(b * 256 + c0 + c)) * 128 + y) * 128 + x4 * 4];
            *(float4*)&lds_t[c][x4 * 4] = v;
        }
        __syncthreads();
        #pragma unroll
        for (int jj = 0; jj < 4; ++jj) {
            int p   = jj * 256 + tid;     // 0..1023
            int x   = p & 127;
            int g   = p >> 7;             // 0..7 (granule of 8 c)
            int cb8 = g * 8;
            u32x4 wv;
            #pragma unroll
            for (int k = 0; k < 4; ++k) {
                float f0 = lds_t[cb8 + 2 * k][x];
                float f1 = lds_t[cb8 + 2 * k + 1][x];
                wv[k] = (u32)f2bf(f0) | ((u32)f2bf(f1) << 16);
            }
            int c  = c0 + cb8;
            int ch = c >> 4;
            int cg = (c >> 3) & 1;
            size_t off = (((((size_t)b * 128 + y) * 16 + ch) * 2 + cg) * 128 + x) * 8;
            *(u32x4*)&feaT[off] = wv;
        }
        __syncthreads();
    }
}

// ---------- kernel 3: MFMA conv (shift-GEMM), 32x32x16, 4x2 tile, 4-wave blocks --
// grid (128 y, 8 b), 256 threads = 4 waves (mw2 x nw2), 1 output row per block
// wave tile: 128 co x 64 px -> 4 A-frags x 2 B-frags = 8 MFMA/tap (4:1 vs ds_read);
// two 4-wave blocks per CU overlap each other's barrier/vmcnt stalls.
__global__ __launch_bounds__(256, 2) void conv_mfma(
        const u16* __restrict__ Wmod,   // fragment-ordered, see modulate_kernel
        const u16* __restrict__ feaT,   // [8][128][16][2][128][8] bf16
        float* __restrict__ out) {      // [8][256][128][128]
    // per-parity: 6144 u16 fea data ([row3][cg2][x128][8ci]) + 24 u16 zero pad
    __shared__ u16 lds[2][6168];        // 24,672 B total

    // XCD swizzle: 1024 wgs = 8 XCDs x 128; each XCD owns one batch b
    const int lin = blockIdx.x + 128 * blockIdx.y;
    const int nid = (lin & 7) * 128 + (lin >> 3);
    const int y   = nid & 127;
    const int b   = nid >> 7;

    const int tid  = threadIdx.x;
    const int lane = tid & 63;
    const int wave = tid >> 6;          // 0..3
    const int mw  = wave & 1;           // co half (128 of 256)
    const int nw  = wave >> 1;          // pixel half (64)
    const int l31 = lane & 31;
    const int l5  = lane >> 5;          // k-group (8 ci)

    // zero both parity pads (24 u16 each)
    if (tid < 24) { lds[0][6144 + tid] = 0; lds[1][6144 + tid] = 0; }

    // ---- precompute all B-side LDS offsets (u16 units, rel. to parity base) ----
    // tap (kh,kw), j: addr = base[kh][j] + kw*8   (kw folded into ds_read imm)
    // boundary combos (kw=0,j=0) and (kw=2,j=1) pre-resolved per lane; y-edge
    // validity folded in (whole row -> zero pad at 6144).
    const int xb0 = nw * 64 + l31 - 1;
    int ofj0[3], ofj1[3], bq0[3], bq2[3];
    #pragma unroll
    for (int kh = 0; kh < 3; ++kh) {
        const int rowb = ((kh * 2 + l5) * 128) * 8;
        const bool rok = (kh == 0) ? (y > 0) : (kh == 2 ? (y < 127) : true);
        const int o0 = rowb + xb0 * 8;      // j=0 base at kw=0
        const int o1 = o0 + 256;            // j=1 base at kw=0
        ofj0[kh] = rok ? o0 : 6144;
        ofj1[kh] = rok ? o1 : 6144;
        bq0[kh]  = (rok && xb0 >= 0)       ? o0        : 6144;   // (kw=0,j=0)
        bq2[kh]  = (rok && xb0 + 34 < 128) ? (o1 + 16) : 6144;   // (kw=2,j=1), +16 = kw*8
    }

    // A-side: cob = mw*4 + i (i=0..3); strides (u16): t=65536, cob=8192, cib=512
    const u16* Abase = Wmod + (size_t)b * 9 * 65536
                            + (size_t)(mw * 4) * 8192 + (size_t)lane * 8;

    auto loadA = [&](int t, int i, int ch) -> s8v {
        return *(const s8v*)(Abase + (size_t)t * 65536 + (size_t)i * 8192 + (size_t)ch * 512);
    };

    // stage one 16-ci chunk: 12 contiguous 1024B DMA units = r(3) x cg(2) x xq(2)
    auto stage = [&](int buf, int ch) {
        u16* ldsb = &lds[buf][0];
        #pragma unroll
        for (int i = 0; i < 3; ++i) {
            int u  = wave + 4 * i;       // 0..11, wave-uniform
            int r  = u >> 2;             // 0..2
            int cg = (u >> 1) & 1;
            int xq = u & 1;
            int gy = y - 1 + r;
            if ((unsigned)gy < 128u) {
                const u16* g = feaT +
                    (((((size_t)b * 128 + gy) * 16 + ch) * 2 + cg) * 128 + xq * 64) * 8
                    + (size_t)lane * 8;
                async_load16(g, ldsb + ((r * 2 + cg) * 128 + xq * 64) * 8);
            }
        }
    };

    f16v acc[4][2];
    #pragma unroll
    for (int i = 0; i < 4; ++i)
        #pragma unroll
        for (int j = 0; j < 2; ++j) acc[i][j] = (f16v)0.0f;

    // A-fragment ring: distance-3 prefetch, 9 taps % 3 == 0 -> static ring index
    s8v fr[3][4];

    // prologue: stage chunk 0, preload taps 0..2 of chunk 0 (full drain once, OK)
    stage(0, 0);
    #pragma unroll
    for (int g = 0; g < 3; ++g)
        #pragma unroll
        for (int i = 0; i < 4; ++i) fr[g][i] = loadA(g, i, 0);
    __syncthreads();

    #pragma unroll 1
    for (int ch = 0; ch < 16; ++ch) {
        const u16* basep = &lds[ch & 1][0];

        // B-fragment double-buffer: bfrE (even taps), bfrO (odd taps).
        // tap t's reads are issued during tap t-1's MFMAs -> LDS latency hidden.
        s8v bfrE[2], bfrO[2];
        {   // tap 0 read (fresh after barrier; one lgkm bubble per chunk)
            const u16* a0 = basep + bq0[0];
            const u16* a1 = basep + ofj1[0];
            bfrE[0] = *(const s8v*)a0;
            bfrE[1] = *(const s8v*)a1;
        }

        #pragma unroll
        for (int t = 0; t < 9; ++t) {
            const int kh1 = (t + 1) / 3, kw1 = (t + 1) % 3;   // next tap (t<8)

            if ((t & 1) == 0) {
                if (t < 8) {
                    const u16* a0 = (kw1 == 0) ? (basep + bq0[kh1]) : (basep + ofj0[kh1] + kw1 * 8);
                    const u16* a1 = (kw1 == 2) ? (basep + bq2[kh1]) : (basep + ofj1[kh1] + kw1 * 8);
                    bfrO[0] = *(const s8v*)a0;
                    bfrO[1] = *(const s8v*)a1;
                }
                __builtin_amdgcn_s_setprio(1);
                #pragma unroll
                for (int i = 0; i < 4; ++i)
                    #pragma unroll
                    for (int j = 0; j < 2; ++j)
                        acc[i][j] = __builtin_amdgcn_mfma_f32_32x32x16_bf16(
                            fr[t % 3][i], bfrE[j], acc[i][j], 0, 0, 0);
                __builtin_amdgcn_s_setprio(0);
            } else {
                const u16* a0 = (kw1 == 0) ? (basep + bq0[kh1]) : (basep + ofj0[kh1] + kw1 * 8);
                const u16* a1 = (kw1 == 2) ? (basep + bq2[kh1]) : (basep + ofj1[kh1] + kw1 * 8);
                bfrE[0] = *(const s8v*)a0;
                bfrE[1] = *(const s8v*)a1;
                __builtin_amdgcn_s_setprio(1);
                #pragma unroll
                for (int i = 0; i < 4; ++i)
                    #pragma unroll
                    for (int j = 0; j < 2; ++j)
                        acc[i][j] = __builtin_amdgcn_mfma_f32_32x32x16_bf16(
                            fr[t % 3][i], bfrO[j], acc[i][j], 0, 0, 0);
                __builtin_amdgcn_s_setprio(0);
            }

            // refill ring slot (t%3) with the fragments needed 3 taps ahead.
            // FIFO: t4/t5 refills are consumed at t7/t8 -> their waits drain the
            // t3 stage DMAs; only taps 6-8 refills (12 entries) live at chunk end.
            if (t < 6) {
                #pragma unroll
                for (int i = 0; i < 4; ++i) fr[t % 3][i] = loadA(t + 3, i, ch);
            } else if (ch < 15) {
                #pragma unroll
                for (int i = 0; i < 4; ++i) fr[t % 3][i] = loadA(t - 6, i, ch + 1);
            }

            if (t == 3 && ch < 15) {
                // pin the DMA's position in the vmem FIFO (vmcnt(12) proof relies on it)
                __builtin_amdgcn_sched_barrier(0);
                stage((ch + 1) & 1, ch + 1);
                __builtin_amdgcn_sched_barrier(0);
            }
        }

        if (ch < 15) {
            // counted-vmcnt barrier (T4): keep the 12 next-chunk A-refills in
            // flight across the barrier; everything older (incl. the stage
            // DMAs) is forced complete. No full drain in the main loop.
            asm volatile("s_waitcnt vmcnt(12)" ::: "memory");
            __builtin_amdgcn_sched_barrier(0);
            __builtin_amdgcn_s_barrier();
            __builtin_amdgcn_sched_barrier(0);
        }
    }

    // epilogue: C/D layout col(n=pixel)=lane&31, row(m=co)=(reg&3)+8*(reg>>2)+4*(lane>>5)
    const int x_base = nw * 64 + l31;
    #pragma unroll
    for (int i = 0; i < 4; ++i) {
        #pragma unroll
        for (int j = 0; j < 2; ++j) {
            #pragma unroll
            for (int reg = 0; reg < 16; ++reg) {
                int co = mw * 128 + i * 32 + (reg & 3) + 8 * (reg >> 2) + 4 * l5;
                out[(((size_t)(b * 256 + co) * 128 + y) * 128) + x_base + j * 32] = acc[i][j][reg];
            }
        }
    }
}

// ---------- launch ----------
extern "C" void kernel_launch(void* const* d_in, const int* in_sizes, int n_in,
                              void* d_out, int out_size, void* d_ws, size_t ws_size,
                              hipStream_t stream) {
    const float* fea       = (const float*)d_in[0];
    const float* norm_feat = (const float*)d_in[1];
    const float* mod_w     = (const float*)d_in[2];
    const float* mod_b     = (const float*)d_in[3];
    const float* weight    = (const float*)d_in[4];
    float* out = (float*)d_out;

    // workspace: Wmod bf16 = 9 MiB, then feaT bf16 = 64 MiB.
    // style (8 KiB fp32) lives at the head of the feaT region (serialized reuse).
    u16* Wmod = (u16*)d_ws;
    u16* feaT = (u16*)((char*)d_ws + 9u * 1024u * 1024u);
    float* style = (float*)feaT;

    style_kernel<<<dim3(8), 256, 0, stream>>>(norm_feat, mod_w, mod_b, style);
    modulate_kernel<<<dim3(256, 8), 256, 0, stream>>>(style, weight, Wmod);
    transpose_kernel<<<dim3(128, 8), 256, 0, stream>>>(fea, feaT);
    conv_mfma<<<dim3(128, 8), 256, 0, stream>>>(Wmod, feaT, out);
}

// Round 7
// 371.877 us; speedup vs baseline: 1.0429x; 1.0265x over previous
//
#include <hip/hip_runtime.h>

typedef unsigned short u16;
typedef unsigned int u32;
typedef short s8v __attribute__((ext_vector_type(8)));    // 8 x bf16 bits (4 VGPRs)
typedef float f16v __attribute__((ext_vector_type(16)));  // 32x32 MFMA accumulator
typedef u32 u32x4 __attribute__((ext_vector_type(4)));

// ---------- helpers ----------
__device__ __forceinline__ u16 f2bf(float f) {
    u32 u = __float_as_uint(f);
    u += 0x7FFFu + ((u >> 16) & 1u);   // round-to-nearest-even
    return (u16)(u >> 16);
}

__device__ __forceinline__ void async_load16(const u16* g, u16* l) {
    // global -> LDS DMA, 16B per lane; LDS dest = wave-uniform base + lane*16
    __builtin_amdgcn_global_load_lds(
        (const __attribute__((address_space(1))) u32*)g,
        (__attribute__((address_space(3))) u32*)l,
        16, 0, 0);
}

// ---------- kernel 0: style (once per b, coalesced mod_w via LDS) ----------
__global__ void style_kernel(const float* __restrict__ norm_feat,  // [8][64]
                             const float* __restrict__ mod_w,      // [256][64]
                             const float* __restrict__ mod_b,      // [256]
                             float* __restrict__ style) {          // [8][256]
    __shared__ float nf[64];
    __shared__ float mw[256][65];
    const int b = blockIdx.x;
    const int tid = threadIdx.x;

    if (tid < 64) nf[tid] = norm_feat[b * 64 + tid];
    #pragma unroll
    for (int i = 0; i < 64; ++i) {
        int idx = i * 256 + tid;
        mw[idx >> 6][idx & 63] = mod_w[idx];
    }
    __syncthreads();

    float s = mod_b[tid];
    #pragma unroll 8
    for (int d = 0; d < 64; ++d) s += nf[d] * mw[tid][d];
    style[b * 256 + tid] = s;
}

// ---------- kernel 1: demod + modulated bf16 weights ----------
// grid (256 co, 8 b), 256 threads (thread = ci)
// Wmod layout for 32x32x16 fragments:
//   [b][t][cob=co>>5 (8)][cib=ci>>4 (16)][lane=(co&31)+32*((ci>>3)&1)][elem=ci&7]
__global__ void modulate_kernel(const float* __restrict__ style,   // [8][256]
                                const float* __restrict__ weight,  // [256][256][9]
                                u16* __restrict__ Wmod) {
    const int co = blockIdx.x;
    const int b  = blockIdx.y;
    const int ci = threadIdx.x;

    __shared__ float red[256];

    const float s = style[b * 256 + ci];

    float w9[9];
    const float* wp = weight + ((size_t)co * 256 + ci) * 9;
    float sq = 0.f;
    #pragma unroll
    for (int t = 0; t < 9; ++t) { w9[t] = wp[t]; sq += w9[t] * w9[t]; }

    red[ci] = sq * s * s;
    __syncthreads();
    for (int off = 128; off > 0; off >>= 1) {
        if (ci < off) red[ci] += red[ci + off];
        __syncthreads();
    }
    const float scale = 1.0f / 48.0f;              // 1/sqrt(256*9)
    const float demod = rsqrtf(scale * scale * red[0] + 1e-8f);
    const float coef  = scale * s * demod;

    // t=0 base; per-t stride = 8*16*64*8 = 65536 u16
    const size_t tile = (((size_t)b * 9 * 8 + (co >> 5)) * 16 + (ci >> 4)) * 512
                      + (size_t)((co & 31) + 32 * ((ci >> 3) & 1)) * 8 + (ci & 7);
    #pragma unroll
    for (int t = 0; t < 9; ++t) {
        Wmod[tile + (size_t)t * 65536] = f2bf(w9[t] * coef);
    }
}

// ---------- kernel 2: NCHW fp32 -> blocked-NHWC bf16 ----------
// feaT layout: [b][y][ch(16)][cg(2)][x(128)][cil(8)] bf16   (c = ch*16 + cg*8 + cil)
// grid (128 y, 4 cblk, 8 b), 256 threads — one 64-c group per block
__global__ __launch_bounds__(256) void transpose_kernel(const float* __restrict__ fea,
                                                        u16* __restrict__ feaT) {
    __shared__ float lds_t[64][132];   // row = 528B -> float4-aligned, 2-way banks
    const int y  = blockIdx.x;
    const int c0 = blockIdx.y * 64;
    const int b  = blockIdx.z;
    const int tid = threadIdx.x;

    #pragma unroll
    for (int r = 0; r < 8; ++r) {
        int i  = r * 256 + tid;       // 0..2047
        int c  = i >> 5;              // 0..63
        int x4 = i & 31;              // float4 index
        float4 v = *(const float4*)&fea[(((size_t)(b * 256 + c0 + c)) * 128 + y) * 128 + x4 * 4];
        *(float4*)&lds_t[c][x4 * 4] = v;
    }
    __syncthreads();
    #pragma unroll
    for (int jj = 0; jj < 4; ++jj) {
        int p   = jj * 256 + tid;     // 0..1023
        int x   = p & 127;
        int g   = p >> 7;             // 0..7 (granule of 8 c)
        int cb8 = g * 8;
        u32x4 wv;
        #pragma unroll
        for (int k = 0; k < 4; ++k) {
            float f0 = lds_t[cb8 + 2 * k][x];
            float f1 = lds_t[cb8 + 2 * k + 1][x];
            wv[k] = (u32)f2bf(f0) | ((u32)f2bf(f1) << 16);
        }
        int c  = c0 + cb8;
        int ch = c >> 4;
        int cg = (c >> 3) & 1;
        size_t off = (((((size_t)b * 128 + y) * 16 + ch) * 2 + cg) * 128 + x) * 8;
        *(u32x4*)&feaT[off] = wv;
    }
}

// ---------- kernel 3: MFMA conv (shift-GEMM), 32x32x16, 128co x 128px wave tile --
// grid (64 y-pairs, 8 b), 256 threads = 4 waves (mw2 x yw2), 2 output rows/block
// wave tile: 128 co x 128 px -> 4 A-frags x 4 B-frags = 16 MFMA/tap.
// A L2 traffic halves vs 128x64 tile (the R2-R6 binding constraint).
// acc = 256 regs -> 1 wave/SIMD; all latency cover is in-wave pipelining.
__global__ __launch_bounds__(256, 1) void conv_mfma(
        const u16* __restrict__ Wmod,   // fragment-ordered, see modulate_kernel
        const u16* __restrict__ feaT,   // [8][128][16][2][128][8] bf16
        float* __restrict__ out) {      // [8][256][128][128]
    // per-parity: 8192 u16 fea ([row4][cg2][x128][8ci]) + 16 u16 zero pad
    __shared__ u16 lds[2][8208];        // 32,832 B

    // XCD swizzle: 512 wgs = 8 XCDs x 64; each XCD owns one batch b
    // -> its 1.18 MiB Wmod slice stays L2-resident.
    const int lin = blockIdx.x + 64 * blockIdx.y;
    const int nid = (lin & 7) * 64 + (lin >> 3);
    const int yp  = nid & 63;           // y-pair: rows 2*yp, 2*yp+1
    const int b   = nid >> 6;

    const int tid  = threadIdx.x;
    const int lane = tid & 63;
    const int wave = tid >> 6;          // 0..3
    const int mw   = wave & 1;          // co half (128 of 256)
    const int ywv  = wave >> 1;         // output row within pair (vector)
    const int l31  = lane & 31;
    const int l5   = lane >> 5;         // k-group (8 ci)

    // wave-uniform scalar copies (drive scalar branches for y-edge taps)
    const int yw_s   = __builtin_amdgcn_readfirstlane(ywv);
    const int y_out_s = 2 * yp + yw_s;
    const bool rokU[3] = { y_out_s > 0, true, y_out_s < 127 };

    // zero both parity pads (16 u16 each)
    if (tid < 16) { lds[0][8192 + tid] = 0; lds[1][8192 + tid] = 0; }

    // ---- B-side LDS offsets (u16 units, rel. to parity base) ----
    // tap (kh,kw), frag j: addr = rb[kh] + j*256 + kw*8 (j,kw folded into imm)
    // x-boundary lanes pre-resolved: (j=0,kw=0) -> bqL, (j=3,kw=2) -> bqR.
    int rb[3], bqL[3], bqR[3];
    #pragma unroll
    for (int kh = 0; kh < 3; ++kh) {
        const int rr = ywv + kh;                      // LDS row 0..3
        const int o  = ((rr * 2 + l5) * 128 + (l31 - 1)) * 8;
        rb[kh]  = o;
        bqL[kh] = (l31 > 0)  ? o : 8192;              // x_in = -1 -> zero pad
        bqR[kh] = (l31 < 31) ? (o + 3 * 256 + 16) : 8192;  // x_in = 128 -> pad
    }

    // A-side: cob = mw*4 + i (i=0..3); strides (u16): t=65536, cob=8192, cib=512
    const u16* Abase = Wmod + (size_t)b * 9 * 65536
                            + (size_t)(mw * 4) * 8192 + (size_t)lane * 8;

    auto loadA = [&](int t, int i, int ch) -> s8v {
        return *(const s8v*)(Abase + (size_t)t * 65536 + (size_t)i * 8192 + (size_t)ch * 512);
    };

    // stage one 16-ci chunk: 16 contiguous 1024B DMA units; wave w covers
    // (cg,xq) = (w>>1, w&1), rows r=0..3.
    auto stage = [&](int buf, int ch) {
        u16* ldsb = &lds[buf][0];
        const int cg = wave >> 1;
        const int xq = wave & 1;
        #pragma unroll
        for (int r = 0; r < 4; ++r) {
            int gy = 2 * yp - 1 + r;
            if ((unsigned)gy < 128u) {
                const u16* g = feaT +
                    (((((size_t)b * 128 + gy) * 16 + ch) * 2 + cg) * 128 + xq * 64) * 8
                    + (size_t)lane * 8;
                async_load16(g, ldsb + ((r * 2 + cg) * 128 + xq * 64) * 8);
            }
        }
    };

    f16v acc[4][4];
    #pragma unroll
    for (int i = 0; i < 4; ++i)
        #pragma unroll
        for (int j = 0; j < 4; ++j) acc[i][j] = (f16v)0.0f;

    // A-fragment ring: distance-3 prefetch, 9 taps % 3 == 0 -> static ring index
    s8v fr[3][4];

    // prologue: stage chunk 0, preload taps 0..2 of chunk 0 (full drain once, OK)
    stage(0, 0);
    #pragma unroll
    for (int g = 0; g < 3; ++g)
        #pragma unroll
        for (int i = 0; i < 4; ++i) fr[g][i] = loadA(g, i, 0);
    __syncthreads();

    #pragma unroll 1
    for (int ch = 0; ch < 16; ++ch) {
        const u16* basep = &lds[ch & 1][0];

        // B read helper: kh,kw,j compile-time under full unroll
        auto readB = [&](int kh, int kw, int j) -> s8v {
            const u16* p;
            if (j == 0 && kw == 0)      p = basep + bqL[kh];
            else if (j == 3 && kw == 2) p = basep + bqR[kh];
            else                        p = basep + rb[kh] + (j * 256 + kw * 8);
            return *(const s8v*)p;
        };

        // B double-buffer: tap t+1's reads issued during tap t's MFMAs.
        s8v bfrE[4], bfrO[4];
        #pragma unroll
        for (int j = 0; j < 4; ++j) bfrE[j] = readB(0, 0, j);   // tap 0 fresh

        #pragma unroll
        for (int t = 0; t < 9; ++t) {
            const int kh = t / 3, kw = t % 3;
            const int khn = (t + 1) / 3, kwn = (t + 1) % 3;

            if ((t & 1) == 0) {
                if (t < 8) {
                    #pragma unroll
                    for (int j = 0; j < 4; ++j) bfrO[j] = readB(khn, kwn, j);
                }
                if (rokU[kh]) {
                    __builtin_amdgcn_s_setprio(1);
                    #pragma unroll
                    for (int i = 0; i < 4; ++i)
                        #pragma unroll
                        for (int j = 0; j < 4; ++j)
                            acc[i][j] = __builtin_amdgcn_mfma_f32_32x32x16_bf16(
                                fr[t % 3][i], bfrE[j], acc[i][j], 0, 0, 0);
                    __builtin_amdgcn_s_setprio(0);
                }
            } else {
                #pragma unroll
                for (int j = 0; j < 4; ++j) bfrE[j] = readB(khn, kwn, j);
                if (rokU[kh]) {
                    __builtin_amdgcn_s_setprio(1);
                    #pragma unroll
                    for (int i = 0; i < 4; ++i)
                        #pragma unroll
                        for (int j = 0; j < 4; ++j)
                            acc[i][j] = __builtin_amdgcn_mfma_f32_32x32x16_bf16(
                                fr[t % 3][i], bfrO[j], acc[i][j], 0, 0, 0);
                    __builtin_amdgcn_s_setprio(0);
                }
            }

            // stage next chunk BEFORE the t3 A-refill so the t6 refill-consume
            // wait drains the stage DMAs (keeps the vmcnt(12) proof valid).
            if (t == 3 && ch < 15) {
                __builtin_amdgcn_sched_barrier(0);
                stage((ch + 1) & 1, ch + 1);
                __builtin_amdgcn_sched_barrier(0);
            }

            // A-ring refill: slot t%3 <- fragment needed 3 taps ahead.
            if (t < 6) {
                #pragma unroll
                for (int i = 0; i < 4; ++i) fr[t % 3][i] = loadA(t + 3, i, ch);
            } else if (ch < 15) {
                #pragma unroll
                for (int i = 0; i < 4; ++i) fr[t % 3][i] = loadA(t - 6, i, ch + 1);
            }
        }

        if (ch < 15) {
            // counted-vmcnt barrier (T4): the 12 next-chunk A-refills (taps 6-8)
            // stay in flight; everything older (incl. stage DMAs) completes.
            asm volatile("s_waitcnt vmcnt(12)" ::: "memory");
            __builtin_amdgcn_sched_barrier(0);
            __builtin_amdgcn_s_barrier();
            __builtin_amdgcn_sched_barrier(0);
        }
    }

    // epilogue: C/D layout col(n=pixel)=lane&31, row(m=co)=(reg&3)+8*(reg>>2)+4*(lane>>5)
    const int y_out = 2 * yp + ywv;
    #pragma unroll
    for (int i = 0; i < 4; ++i) {
        #pragma unroll
        for (int j = 0; j < 4; ++j) {
            #pragma unroll
            for (int reg = 0; reg < 16; ++reg) {
                int co = mw * 128 + i * 32 + (reg & 3) + 8 * (reg >> 2) + 4 * l5;
                int x  = j * 32 + l31;
                out[(((size_t)(b * 256 + co) * 128 + y_out) * 128) + x] = acc[i][j][reg];
            }
        }
    }
}

// ---------- launch ----------
extern "C" void kernel_launch(void* const* d_in, const int* in_sizes, int n_in,
                              void* d_out, int out_size, void* d_ws, size_t ws_size,
                              hipStream_t stream) {
    const float* fea       = (const float*)d_in[0];
    const float* norm_feat = (const float*)d_in[1];
    const float* mod_w     = (const float*)d_in[2];
    const float* mod_b     = (const float*)d_in[3];
    const float* weight    = (const float*)d_in[4];
    float* out = (float*)d_out;

    // workspace: Wmod bf16 = 9 MiB, then feaT bf16 = 64 MiB.
    // style (8 KiB fp32) lives at the head of the feaT region (serialized reuse).
    u16* Wmod = (u16*)d_ws;
    u16* feaT = (u16*)((char*)d_ws + 9u * 1024u * 1024u);
    float* style = (float*)feaT;

    style_kernel<<<dim3(8), 256, 0, stream>>>(norm_feat, mod_w, mod_b, style);
    modulate_kernel<<<dim3(256, 8), 256, 0, stream>>>(style, weight, Wmod);
    transpose_kernel<<<dim3(128, 4, 8), 256, 0, stream>>>(fea, feaT);
    conv_mfma<<<dim3(64, 8), 256, 0, stream>>>(Wmod, feaT, out);
}

// Round 8
// 370.312 us; speedup vs baseline: 1.0473x; 1.0042x over previous
//
#include <hip/hip_runtime.h>

typedef unsigned short u16;
typedef unsigned int u32;
typedef short s8v __attribute__((ext_vector_type(8)));    // 8 x bf16 bits (4 VGPRs)
typedef float f16v __attribute__((ext_vector_type(16)));  // 32x32 MFMA accumulator
typedef u32 u32x4 __attribute__((ext_vector_type(4)));

// ---------- helpers ----------
__device__ __forceinline__ u16 f2bf(float f) {
    u32 u = __float_as_uint(f);
    u += 0x7FFFu + ((u >> 16) & 1u);   // round-to-nearest-even
    return (u16)(u >> 16);
}

__device__ __forceinline__ void async_load16(const u16* g, u16* l) {
    // global -> LDS DMA, 16B per lane; LDS dest = wave-uniform base + lane*16
    __builtin_amdgcn_global_load_lds(
        (const __attribute__((address_space(1))) u32*)g,
        (__attribute__((address_space(3))) u32*)l,
        16, 0, 0);
}

// ---------- kernel 0: style (once per b, coalesced mod_w via LDS) ----------
__global__ void style_kernel(const float* __restrict__ norm_feat,  // [8][64]
                             const float* __restrict__ mod_w,      // [256][64]
                             const float* __restrict__ mod_b,      // [256]
                             float* __restrict__ style) {          // [8][256]
    __shared__ float nf[64];
    __shared__ float mw[256][65];
    const int b = blockIdx.x;
    const int tid = threadIdx.x;

    if (tid < 64) nf[tid] = norm_feat[b * 64 + tid];
    #pragma unroll
    for (int i = 0; i < 64; ++i) {
        int idx = i * 256 + tid;
        mw[idx >> 6][idx & 63] = mod_w[idx];
    }
    __syncthreads();

    float s = mod_b[tid];
    #pragma unroll 8
    for (int d = 0; d < 64; ++d) s += nf[d] * mw[tid][d];
    style[b * 256 + tid] = s;
}

// ---------- kernel 1: demod + modulated bf16 weights ----------
// grid (256 co, 8 b), 256 threads (thread = ci)
// Wmod layout for 32x32x16 fragments:
//   [b][t][cob=co>>5 (8)][cib=ci>>4 (16)][lane=(co&31)+32*((ci>>3)&1)][elem=ci&7]
// weight[co] slice (2304 floats, contiguous) staged in LDS via coalesced loads
// -> kills the 36B-strided per-thread reads (9x overfetch).
__global__ void modulate_kernel(const float* __restrict__ style,   // [8][256]
                                const float* __restrict__ weight,  // [256][256][9]
                                u16* __restrict__ Wmod) {
    const int co = blockIdx.x;
    const int b  = blockIdx.y;
    const int ci = threadIdx.x;

    __shared__ float wlds[2304];
    __shared__ float red[256];

    const float* wsrc = weight + (size_t)co * 2304;
    #pragma unroll
    for (int i = 0; i < 9; ++i) wlds[i * 256 + ci] = wsrc[i * 256 + ci];

    const float s = style[b * 256 + ci];
    __syncthreads();

    // per-thread 9 taps from LDS: addr stride 9, gcd(9,32)=1 -> conflict-free
    float w9[9];
    float sq = 0.f;
    #pragma unroll
    for (int t = 0; t < 9; ++t) { w9[t] = wlds[ci * 9 + t]; sq += w9[t] * w9[t]; }

    red[ci] = sq * s * s;
    __syncthreads();
    for (int off = 128; off > 0; off >>= 1) {
        if (ci < off) red[ci] += red[ci + off];
        __syncthreads();
    }
    const float scale = 1.0f / 48.0f;              // 1/sqrt(256*9)
    const float demod = rsqrtf(scale * scale * red[0] + 1e-8f);
    const float coef  = scale * s * demod;

    // t=0 base; per-t stride = 8*16*64*8 = 65536 u16
    const size_t tile = (((size_t)b * 9 * 8 + (co >> 5)) * 16 + (ci >> 4)) * 512
                      + (size_t)((co & 31) + 32 * ((ci >> 3) & 1)) * 8 + (ci & 7);
    #pragma unroll
    for (int t = 0; t < 9; ++t) {
        Wmod[tile + (size_t)t * 65536] = f2bf(w9[t] * coef);
    }
}

// ---------- kernel 2: NCHW fp32 -> blocked-NHWC bf16, LDS-free direct pack ------
// feaT layout: [b][y][ch(16)][cg(2)][x(128)][cil(8)] bf16   (c = ch*16 + cg*8 + cil)
// One thread per 16B output granule (8 consecutive c at fixed b,y,x):
//   8 dword loads, each coalesced 256B/wave (x consecutive across lanes),
//   pack to 4xu32, one 16B store (1KB/wave contiguous). No LDS, no barriers.
// grid 16384 blocks x 256 threads = 4.19M threads
__global__ __launch_bounds__(256) void transpose_kernel(const float* __restrict__ fea,
                                                        u16* __restrict__ feaT) {
    const int idx = blockIdx.x * 256 + threadIdx.x;   // 0 .. 2^22-1
    const int x   = idx & 127;
    const int g   = (idx >> 7) & 31;    // granule of 8 c
    const int y   = (idx >> 12) & 127;
    const int b   = idx >> 19;
    const int c0  = g * 8;

    const float* src = fea + (((size_t)(b * 256 + c0) * 128 + y) * 128 + x);
    float f[8];
    #pragma unroll
    for (int k = 0; k < 8; ++k) f[k] = src[(size_t)k * 16384];   // c stride = 128*128

    u32x4 wv;
    #pragma unroll
    for (int k = 0; k < 4; ++k)
        wv[k] = (u32)f2bf(f[2 * k]) | ((u32)f2bf(f[2 * k + 1]) << 16);

    const int ch = g >> 1;
    const int cg = g & 1;
    const size_t off = (((((size_t)b * 128 + y) * 16 + ch) * 2 + cg) * 128 + x) * 8;
    *(u32x4*)&feaT[off] = wv;
}

// ---------- kernel 3: MFMA conv (shift-GEMM), 32x32x16, 128co x 128px wave tile --
// grid (64 y-pairs, 8 b), 256 threads = 4 waves (mw2 x yw2), 2 output rows/block
// Identical to R7 except setprio removed (m190: ~0/negative on lockstep
// barrier structures like this one).
__global__ __launch_bounds__(256, 1) void conv_mfma(
        const u16* __restrict__ Wmod,   // fragment-ordered, see modulate_kernel
        const u16* __restrict__ feaT,   // [8][128][16][2][128][8] bf16
        float* __restrict__ out) {      // [8][256][128][128]
    // per-parity: 8192 u16 fea ([row4][cg2][x128][8ci]) + 16 u16 zero pad
    __shared__ u16 lds[2][8208];        // 32,832 B

    // XCD swizzle: 512 wgs = 8 XCDs x 64; each XCD owns one batch b
    const int lin = blockIdx.x + 64 * blockIdx.y;
    const int nid = (lin & 7) * 64 + (lin >> 3);
    const int yp  = nid & 63;           // y-pair: rows 2*yp, 2*yp+1
    const int b   = nid >> 6;

    const int tid  = threadIdx.x;
    const int lane = tid & 63;
    const int wave = tid >> 6;          // 0..3
    const int mw   = wave & 1;          // co half (128 of 256)
    const int ywv  = wave >> 1;         // output row within pair (vector)
    const int l31  = lane & 31;
    const int l5   = lane >> 5;         // k-group (8 ci)

    // wave-uniform scalar copies (drive scalar branches for y-edge taps)
    const int yw_s   = __builtin_amdgcn_readfirstlane(ywv);
    const int y_out_s = 2 * yp + yw_s;
    const bool rokU[3] = { y_out_s > 0, true, y_out_s < 127 };

    // zero both parity pads (16 u16 each)
    if (tid < 16) { lds[0][8192 + tid] = 0; lds[1][8192 + tid] = 0; }

    // ---- B-side LDS offsets (u16 units, rel. to parity base) ----
    int rb[3], bqL[3], bqR[3];
    #pragma unroll
    for (int kh = 0; kh < 3; ++kh) {
        const int rr = ywv + kh;                      // LDS row 0..3
        const int o  = ((rr * 2 + l5) * 128 + (l31 - 1)) * 8;
        rb[kh]  = o;
        bqL[kh] = (l31 > 0)  ? o : 8192;              // x_in = -1 -> zero pad
        bqR[kh] = (l31 < 31) ? (o + 3 * 256 + 16) : 8192;  // x_in = 128 -> pad
    }

    // A-side: cob = mw*4 + i (i=0..3); strides (u16): t=65536, cob=8192, cib=512
    const u16* Abase = Wmod + (size_t)b * 9 * 65536
                            + (size_t)(mw * 4) * 8192 + (size_t)lane * 8;

    auto loadA = [&](int t, int i, int ch) -> s8v {
        return *(const s8v*)(Abase + (size_t)t * 65536 + (size_t)i * 8192 + (size_t)ch * 512);
    };

    // stage one 16-ci chunk: 16 contiguous 1024B DMA units; wave w covers
    // (cg,xq) = (w>>1, w&1), rows r=0..3.
    auto stage = [&](int buf, int ch) {
        u16* ldsb = &lds[buf][0];
        const int cg = wave >> 1;
        const int xq = wave & 1;
        #pragma unroll
        for (int r = 0; r < 4; ++r) {
            int gy = 2 * yp - 1 + r;
            if ((unsigned)gy < 128u) {
                const u16* g = feaT +
                    (((((size_t)b * 128 + gy) * 16 + ch) * 2 + cg) * 128 + xq * 64) * 8
                    + (size_t)lane * 8;
                async_load16(g, ldsb + ((r * 2 + cg) * 128 + xq * 64) * 8);
            }
        }
    };

    f16v acc[4][4];
    #pragma unroll
    for (int i = 0; i < 4; ++i)
        #pragma unroll
        for (int j = 0; j < 4; ++j) acc[i][j] = (f16v)0.0f;

    // A-fragment ring: distance-3 prefetch, 9 taps % 3 == 0 -> static ring index
    s8v fr[3][4];

    // prologue: stage chunk 0, preload taps 0..2 of chunk 0 (full drain once, OK)
    stage(0, 0);
    #pragma unroll
    for (int g = 0; g < 3; ++g)
        #pragma unroll
        for (int i = 0; i < 4; ++i) fr[g][i] = loadA(g, i, 0);
    __syncthreads();

    #pragma unroll 1
    for (int ch = 0; ch < 16; ++ch) {
        const u16* basep = &lds[ch & 1][0];

        // B read helper: kh,kw,j compile-time under full unroll
        auto readB = [&](int kh, int kw, int j) -> s8v {
            const u16* p;
            if (j == 0 && kw == 0)      p = basep + bqL[kh];
            else if (j == 3 && kw == 2) p = basep + bqR[kh];
            else                        p = basep + rb[kh] + (j * 256 + kw * 8);
            return *(const s8v*)p;
        };

        // B double-buffer: tap t+1's reads issued during tap t's MFMAs.
        s8v bfrE[4], bfrO[4];
        #pragma unroll
        for (int j = 0; j < 4; ++j) bfrE[j] = readB(0, 0, j);   // tap 0 fresh

        #pragma unroll
        for (int t = 0; t < 9; ++t) {
            const int kh = t / 3;
            const int khn = (t + 1) / 3, kwn = (t + 1) % 3;

            if ((t & 1) == 0) {
                if (t < 8) {
                    #pragma unroll
                    for (int j = 0; j < 4; ++j) bfrO[j] = readB(khn, kwn, j);
                }
                if (rokU[kh]) {
                    #pragma unroll
                    for (int i = 0; i < 4; ++i)
                        #pragma unroll
                        for (int j = 0; j < 4; ++j)
                            acc[i][j] = __builtin_amdgcn_mfma_f32_32x32x16_bf16(
                                fr[t % 3][i], bfrE[j], acc[i][j], 0, 0, 0);
                }
            } else {
                #pragma unroll
                for (int j = 0; j < 4; ++j) bfrE[j] = readB(khn, kwn, j);
                if (rokU[kh]) {
                    #pragma unroll
                    for (int i = 0; i < 4; ++i)
                        #pragma unroll
                        for (int j = 0; j < 4; ++j)
                            acc[i][j] = __builtin_amdgcn_mfma_f32_32x32x16_bf16(
                                fr[t % 3][i], bfrO[j], acc[i][j], 0, 0, 0);
                }
            }

            // stage next chunk BEFORE the t3 A-refill so the t6 refill-consume
            // wait drains the stage DMAs (keeps the vmcnt(12) proof valid).
            if (t == 3 && ch < 15) {
                __builtin_amdgcn_sched_barrier(0);
                stage((ch + 1) & 1, ch + 1);
                __builtin_amdgcn_sched_barrier(0);
            }

            // A-ring refill: slot t%3 <- fragment needed 3 taps ahead.
            // (must stay AFTER the MFMA block: it overwrites fr[t%3])
            if (t < 6) {
                #pragma unroll
                for (int i = 0; i < 4; ++i) fr[t % 3][i] = loadA(t + 3, i, ch);
            } else if (ch < 15) {
                #pragma unroll
                for (int i = 0; i < 4; ++i) fr[t % 3][i] = loadA(t - 6, i, ch + 1);
            }
        }

        if (ch < 15) {
            // counted-vmcnt barrier (T4): the 12 next-chunk A-refills (taps 6-8)
            // stay in flight; everything older (incl. stage DMAs) completes.
            asm volatile("s_waitcnt vmcnt(12)" ::: "memory");
            __builtin_amdgcn_sched_barrier(0);
            __builtin_amdgcn_s_barrier();
            __builtin_amdgcn_sched_barrier(0);
        }
    }

    // epilogue: C/D layout col(n=pixel)=lane&31, row(m=co)=(reg&3)+8*(reg>>2)+4*(lane>>5)
    const int y_out = 2 * yp + ywv;
    #pragma unroll
    for (int i = 0; i < 4; ++i) {
        #pragma unroll
        for (int j = 0; j < 4; ++j) {
            #pragma unroll
            for (int reg = 0; reg < 16; ++reg) {
                int co = mw * 128 + i * 32 + (reg & 3) + 8 * (reg >> 2) + 4 * l5;
                int x  = j * 32 + l31;
                out[(((size_t)(b * 256 + co) * 128 + y_out) * 128) + x] = acc[i][j][reg];
            }
        }
    }
}

// ---------- launch ----------
extern "C" void kernel_launch(void* const* d_in, const int* in_sizes, int n_in,
                              void* d_out, int out_size, void* d_ws, size_t ws_size,
                              hipStream_t stream) {
    const float* fea       = (const float*)d_in[0];
    const float* norm_feat = (const float*)d_in[1];
    const float* mod_w     = (const float*)d_in[2];
    const float* mod_b     = (const float*)d_in[3];
    const float* weight    = (const float*)d_in[4];
    float* out = (float*)d_out;

    // workspace: Wmod bf16 = 9 MiB, then feaT bf16 = 64 MiB.
    // style (8 KiB fp32) lives at the head of the feaT region (serialized reuse).
    u16* Wmod = (u16*)d_ws;
    u16* feaT = (u16*)((char*)d_ws + 9u * 1024u * 1024u);
    float* style = (float*)feaT;

    style_kernel<<<dim3(8), 256, 0, stream>>>(norm_feat, mod_w, mod_b, style);
    modulate_kernel<<<dim3(256, 8), 256, 0, stream>>>(style, weight, Wmod);
    transpose_kernel<<<dim3(16384), 256, 0, stream>>>(fea, feaT);
    conv_mfma<<<dim3(64, 8), 256, 0, stream>>>(Wmod, feaT, out);
}